// Round 2
// baseline (479.399 us; speedup 1.0000x reference)
//
#include <hip/hip_runtime.h>
#include <hip/hip_bf16.h>

// Shapes
#define B_   128
#define S_   400
#define H_   512
#define V_   50257
#define VX_  50307

// Output offsets (floats, concatenated in return order)
#define OFF_FINAL 0
#define OFF_PGEN  6439296
#define OFF_ATTN  6439424
#define OFF_COV   6490624
#define OFF_H1    6541824
#define OFF_C1    6607360
#define OFF_DEC   6672896

typedef __attribute__((ext_vector_type(8))) short bf16x8;
typedef __attribute__((ext_vector_type(4))) float f32x4;

static __device__ __forceinline__ float sigmoid_f(float x) {
    return 1.0f / (1.0f + __expf(-x));
}
static __device__ __forceinline__ float tanh_f(float x) {
    return 1.0f - 2.0f / (__expf(2.0f * x) + 1.0f);
}
// f32x2 -> packed bf16x2 (RNE) — v_cvt_pk_bf16_f32 on gfx950
static __device__ __forceinline__ unsigned int pk2(float x, float y) {
    union { __hip_bfloat162 h; unsigned int u; } cv;
    cv.h = __float22bfloat162_rn(make_float2(x, y));
    return cv.u;
}

// Zero the split-K accumulation region of ws (w_x, w_decfea, w_gates, w_pga
// laid out contiguously: 393344 floats = 98336 float4) + o_dec (16384 float4).
__global__ __launch_bounds__(256) void zero_ws(
    float4* __restrict__ ws4, float4* __restrict__ dec4)
{
    const int i = blockIdx.x * 256 + threadIdx.x;
    const float4 z = make_float4(0.f, 0.f, 0.f, 0.f);
    if (i < 98336) ws4[i] = z;
    if (i < 16384) dec4[i] = z;
}

// ---------------------------------------------------------------------------
// Generic small GEMM (unchanged): C[128 x N] (+)= A1@W1^T (+ A2@W2^T) + bias1.
// Split-K via grid.y with atomic epilogue; optional fused p_gen dot.
// ---------------------------------------------------------------------------
template <int NT>
__global__ __launch_bounds__(256) void gemm_mfma(
    const float* __restrict__ A1, const float* __restrict__ W1, int ldw1, int kwo1,
    const float* __restrict__ A2, const float* __restrict__ W2, int ldw2, int kwo2,
    const float* __restrict__ bias1,
    float* __restrict__ C, int N,
    const float* __restrict__ wpg, float* __restrict__ pgen_acc)
{
    __shared__ __align__(16) unsigned short As[128 * 40];
    __shared__ __align__(16) unsigned short Ws[NT * 16 * 40];
    const int tid  = threadIdx.x;
    const int bn0  = blockIdx.x * (NT * 16);
    const int lane = tid & 63;
    const int wv   = tid >> 6;
    const int quad = lane >> 4;
    const int col  = lane & 15;

    f32x4 acc[2][NT];
#pragma unroll
    for (int i = 0; i < 2; ++i)
#pragma unroll
        for (int j = 0; j < NT; ++j) acc[i][j] = (f32x4){0.f, 0.f, 0.f, 0.f};

    const int ar = tid >> 1;
    const int ac = (tid & 1) << 4;
    const int wr = (NT == 8) ? (tid >> 1) : (tid >> 2);
    const int wc = (NT == 8) ? ((tid & 1) << 4) : ((tid & 3) << 3);
    const int wrg = (bn0 + wr < N) ? (bn0 + wr) : (N - 1);

    const int Ktot = (A2 != nullptr) ? 1024 : 512;
    const int KC   = Ktot / gridDim.y;
    const int kg0  = blockIdx.y * KC;
    const int nsteps = KC >> 5;

    const float* ApB[2];
    const float* WpB[2];
    ApB[0] = A1 + (long)ar * 512 + ac;
    WpB[0] = W1 + (long)wrg * ldw1 + kwo1 + wc;
    ApB[1] = A2 ? (A2 + (long)ar * 512 + ac) : ApB[0];
    WpB[1] = W2 ? (W2 + (long)wrg * ldw2 + kwo2 + wc) : WpB[0];

    float4 aC[4], wC[NT / 2], aN[4], wN[NT / 2];

    auto fetch = [&](int s, float4* a, float4* w) {
        const int kg = kg0 + (s << 5);
        const int ph = kg >> 9;
        const int k0 = kg & 511;
        const float* Ap = ApB[ph] + k0;
        const float* Wp = WpB[ph] + k0;
#pragma unroll
        for (int i = 0; i < 4; ++i) a[i] = *(const float4*)(Ap + i * 4);
#pragma unroll
        for (int i = 0; i < NT / 2; ++i) w[i] = *(const float4*)(Wp + i * 4);
    };

    fetch(0, aC, wC);
    for (int s = 0; s < nsteps; ++s) {
        __syncthreads();
        uint4* apd = (uint4*)&As[ar * 40 + ac];
        apd[0] = make_uint4(pk2(aC[0].x, aC[0].y), pk2(aC[0].z, aC[0].w),
                            pk2(aC[1].x, aC[1].y), pk2(aC[1].z, aC[1].w));
        apd[1] = make_uint4(pk2(aC[2].x, aC[2].y), pk2(aC[2].z, aC[2].w),
                            pk2(aC[3].x, aC[3].y), pk2(aC[3].z, aC[3].w));
        uint4* wpd = (uint4*)&Ws[wr * 40 + wc];
        wpd[0] = make_uint4(pk2(wC[0].x, wC[0].y), pk2(wC[0].z, wC[0].w),
                            pk2(wC[1].x, wC[1].y), pk2(wC[1].z, wC[1].w));
        if (NT == 8)
            wpd[1] = make_uint4(pk2(wC[2].x, wC[2].y), pk2(wC[2].z, wC[2].w),
                                pk2(wC[3].x, wC[3].y), pk2(wC[3].z, wC[3].w));
        __syncthreads();

        if (s + 1 < nsteps) fetch(s + 1, aN, wN);

        const bf16x8 aF0 = *(const bf16x8*)&As[(wv * 32 + col) * 40 + quad * 8];
        const bf16x8 aF1 = *(const bf16x8*)&As[(wv * 32 + 16 + col) * 40 + quad * 8];
#pragma unroll
        for (int ni = 0; ni < NT; ++ni) {
            const bf16x8 bF = *(const bf16x8*)&Ws[(ni * 16 + col) * 40 + quad * 8];
            acc[0][ni] = __builtin_amdgcn_mfma_f32_16x16x32_bf16(aF0, bF, acc[0][ni], 0, 0, 0);
            acc[1][ni] = __builtin_amdgcn_mfma_f32_16x16x32_bf16(aF1, bF, acc[1][ni], 0, 0, 0);
        }
#pragma unroll
        for (int i = 0; i < 4; ++i) aC[i] = aN[i];
#pragma unroll
        for (int i = 0; i < NT / 2; ++i) wC[i] = wN[i];
    }

    const bool split = (gridDim.y > 1);
    const bool addb  = (!split) || (blockIdx.y == 0);

    float pgp[2][4];
#pragma unroll
    for (int i = 0; i < 2; ++i)
#pragma unroll
        for (int r = 0; r < 4; ++r) pgp[i][r] = 0.f;

#pragma unroll
    for (int mi = 0; mi < 2; ++mi) {
#pragma unroll
        for (int ni = 0; ni < NT; ++ni) {
            const int n = bn0 + ni * 16 + col;
            if (n < N) {
                const float bv = addb ? bias1[n] : 0.f;
                const float wpv = wpg ? wpg[n] : 0.f;
#pragma unroll
                for (int r = 0; r < 4; ++r) {
                    const int m = wv * 32 + mi * 16 + quad * 4 + r;
                    const float v = acc[mi][ni][r] + bv;
                    if (split) atomicAdd(&C[(long)m * N + n], v);
                    else       C[(long)m * N + n] = v;
                    pgp[mi][r] += v * wpv;
                }
            }
        }
    }
    if (wpg) {
#pragma unroll
        for (int mi = 0; mi < 2; ++mi)
#pragma unroll
            for (int r = 0; r < 4; ++r) {
                float v = pgp[mi][r];
                v += __shfl_xor(v, 1); v += __shfl_xor(v, 2);
                v += __shfl_xor(v, 4); v += __shfl_xor(v, 8);
                if (col == 0) {
                    const int m = wv * 32 + mi * 16 + quad * 4 + r;
                    atomicAdd(&pgen_acc[m], v);
                }
            }
    }
}

// ---------------------------------------------------------------------------
// Vocab GEMM: C[128 x N] = A[128x512] @ W^T + bias, fused row-softmax partials.
// Block = 4 waves; decode bx -> (nb, mb): block covers M rows [mb*64, mb*64+64)
// x N cols [nb*128, nb*128+128); wave w owns 32 cols (2 x 16-col MFMA groups).
// A staged ONCE in 64KB XOR-swizzled bf16 LDS (1 barrier); W fragments loaded
// straight from global into registers (no LDS, no per-step barriers), rolling
// 4-step prefetch, pk2 conversion in-register. Per-block row stats (max,
// exp-sum over the 128-col tile) reduced via reused LDS -> pm/ps[393/row].
// ---------------------------------------------------------------------------
__global__ __launch_bounds__(256) void vocab_gemm(
    const float* __restrict__ A, const float* __restrict__ W,
    const float* __restrict__ bias,
    float* __restrict__ C, int N,
    float* __restrict__ pm, float* __restrict__ ps, int nbn)
{
    __shared__ __align__(16) unsigned short As[64 * 512];  // 64 KB
    const int tid  = threadIdx.x;
    const int lane = tid & 63;
    const int w    = tid >> 6;
    const int quad = lane >> 4;
    const int c    = lane & 15;
    const int nb   = blockIdx.x >> 1;
    const int mb   = blockIdx.x & 1;

    int n_[2], nc_[2];
    const float* Wp[2];
#pragma unroll
    for (int ni = 0; ni < 2; ++ni) {
        n_[ni]  = nb * 128 + w * 32 + ni * 16 + c;
        nc_[ni] = (n_[ni] < N) ? n_[ni] : (N - 1);
        Wp[ni]  = W + (long)nc_[ni] * 512 + quad * 8;
    }

    f32x4 acc[4][2];
#pragma unroll
    for (int mt = 0; mt < 4; ++mt)
#pragma unroll
        for (int ni = 0; ni < 2; ++ni) acc[mt][ni] = (f32x4){0.f, 0.f, 0.f, 0.f};

    // rolling 4-step W prefetch (static indices via full unroll)
    float4 wpre[4][2][2];
#pragma unroll
    for (int sl = 0; sl < 4; ++sl)
#pragma unroll
        for (int ni = 0; ni < 2; ++ni) {
            wpre[sl][ni][0] = *(const float4*)(Wp[ni] + sl * 32);
            wpre[sl][ni][1] = *(const float4*)(Wp[ni] + sl * 32 + 4);
        }

    // stage A[mb*64 .. +64][0..512) as bf16, XOR-swizzled at 16B granularity
    {
        const int r   = tid >> 2;
        const int kk0 = (tid & 3) << 7;
        const float* Ap = A + (long)(mb * 64 + r) * 512 + kk0;
        const int swz = (r & 7) << 3;
#pragma unroll
        for (int i = 0; i < 16; ++i) {
            const float4 x = *(const float4*)(Ap + i * 8);
            const float4 y = *(const float4*)(Ap + i * 8 + 4);
            const int idx = r * 512 + ((kk0 + i * 8) ^ swz);
            *(uint4*)&As[idx] = make_uint4(pk2(x.x, x.y), pk2(x.z, x.w),
                                           pk2(y.x, y.y), pk2(y.z, y.w));
        }
    }
    __syncthreads();

#pragma unroll
    for (int sl = 0; sl < 16; ++sl) {
        union { bf16x8 v; uint4 q; } bu[2];
#pragma unroll
        for (int ni = 0; ni < 2; ++ni) {
            const float4 a = wpre[sl & 3][ni][0];
            const float4 b = wpre[sl & 3][ni][1];
            bu[ni].q = make_uint4(pk2(a.x, a.y), pk2(a.z, a.w),
                                  pk2(b.x, b.y), pk2(b.z, b.w));
        }
        const int kq = sl * 32 + quad * 8;
#pragma unroll
        for (int mt = 0; mt < 4; ++mt) {
            const int row = mt * 16 + c;
            const bf16x8 aF =
                *(const bf16x8*)&As[row * 512 + (kq ^ ((row & 7) << 3))];
            acc[mt][0] = __builtin_amdgcn_mfma_f32_16x16x32_bf16(aF, bu[0].v, acc[mt][0], 0, 0, 0);
            acc[mt][1] = __builtin_amdgcn_mfma_f32_16x16x32_bf16(aF, bu[1].v, acc[mt][1], 0, 0, 0);
        }
        if (sl + 4 < 16) {
#pragma unroll
            for (int ni = 0; ni < 2; ++ni) {
                wpre[sl & 3][ni][0] = *(const float4*)(Wp[ni] + (sl + 4) * 32);
                wpre[sl & 3][ni][1] = *(const float4*)(Wp[ni] + (sl + 4) * 32 + 4);
            }
        }
    }

    __syncthreads();               // all As reads done; reuse As as scratch
    float* redM = (float*)As;      // [64][8]
    float* redS = (float*)As + 512;

#pragma unroll
    for (int ni = 0; ni < 2; ++ni) {
        const bool ok = (n_[ni] < N);
        const float bv = bias[nc_[ni]];
#pragma unroll
        for (int mt = 0; mt < 4; ++mt) {
#pragma unroll
            for (int r = 0; r < 4; ++r) {
                const float v = acc[mt][ni][r] + bv;
                float mx = ok ? v : -3.0e38f;
                mx = fmaxf(mx, __shfl_xor(mx, 1));
                mx = fmaxf(mx, __shfl_xor(mx, 2));
                mx = fmaxf(mx, __shfl_xor(mx, 4));
                mx = fmaxf(mx, __shfl_xor(mx, 8));
                float sv = ok ? __expf(v - mx) : 0.f;
                sv += __shfl_xor(sv, 1);
                sv += __shfl_xor(sv, 2);
                sv += __shfl_xor(sv, 4);
                sv += __shfl_xor(sv, 8);
                const int mloc = mt * 16 + quad * 4 + r;
                if (ok) C[(long)(mb * 64 + mloc) * N + n_[ni]] = v;
                if (c == 0) {
                    redM[mloc * 8 + w * 2 + ni] = mx;
                    redS[mloc * 8 + w * 2 + ni] = sv;
                }
            }
        }
    }
    __syncthreads();
    if (tid < 64) {
        float M = -3.0e38f;
#pragma unroll
        for (int i = 0; i < 8; ++i) M = fmaxf(M, redM[tid * 8 + i]);
        float S = 0.f;
#pragma unroll
        for (int i = 0; i < 8; ++i) S += redS[tid * 8 + i] * __expf(redM[tid * 8 + i] - M);
        const long m = mb * 64 + tid;
        pm[m * nbn + nb] = M;
        ps[m * nbn + nb] = S;
    }
}

// Elementwise LSTM cell over the accumulated gates buffer [128 x 2048]
// (i,f,g,o column-stacked). b_ih was added by the gates GEMM; add b_hh here.
__global__ __launch_bounds__(256) void lstm_cell(
    const float* __restrict__ gates, const float* __restrict__ bhh,
    const float* __restrict__ c0,
    float* __restrict__ h1, float* __restrict__ c1)
{
    const int idx = blockIdx.x * 256 + threadIdx.x;  // 65536 = 128*512
    const int m = idx >> 9;
    const int h = idx & 511;
    const float* g = gates + (long)m * 2048;
    const float iv = sigmoid_f(g[h]        + bhh[h]);
    const float fv = sigmoid_f(g[512 + h]  + bhh[512 + h]);
    const float gv = tanh_f   (g[1024 + h] + bhh[1024 + h]);
    const float ov = sigmoid_f(g[1536 + h] + bhh[1536 + h]);
    const float c = fv * c0[idx] + iv * gv;
    c1[idx] = c;
    h1[idx] = ov * tanh_f(c);
}

// e[b,s] = sum_h tanh(sf[b,s,h] + dec_fea[b,h] + wc*cov[b,s]) * v_att[h]
__global__ __launch_bounds__(256) void attn_scores(
    const float* __restrict__ sfeat, const float* __restrict__ decfea,
    const float* __restrict__ cov, const float* __restrict__ wc,
    const float* __restrict__ vatt, float* __restrict__ e)
{
    const int lane = threadIdx.x & 63;
    const int pair = blockIdx.x * 4 + (threadIdx.x >> 6);  // b*400+s
    const int b = pair / 400;
    const float cc = wc[0] * cov[pair];
    const float* sp = sfeat + ((long)pair << 9) + (lane << 3);
    const float* dp = decfea + (b << 9) + (lane << 3);
    const float* vp = vatt + (lane << 3);
    const float4 s0 = *(const float4*)sp, s1 = *(const float4*)(sp + 4);
    const float4 d0 = *(const float4*)dp, d1 = *(const float4*)(dp + 4);
    const float4 v0 = *(const float4*)vp, v1 = *(const float4*)(vp + 4);
    float acc = tanh_f(s0.x + d0.x + cc) * v0.x
              + tanh_f(s0.y + d0.y + cc) * v0.y
              + tanh_f(s0.z + d0.z + cc) * v0.z
              + tanh_f(s0.w + d0.w + cc) * v0.w
              + tanh_f(s1.x + d1.x + cc) * v1.x
              + tanh_f(s1.y + d1.y + cc) * v1.y
              + tanh_f(s1.z + d1.z + cc) * v1.z
              + tanh_f(s1.w + d1.w + cc) * v1.w;
#pragma unroll
    for (int off = 32; off > 0; off >>= 1) acc += __shfl_down(acc, off);
    if (lane == 0) e[pair] = acc;
}

// Masked softmax over S per batch row + coverage update; also zeroes ctx accum.
__global__ __launch_bounds__(256) void attn_softmax(
    const float* __restrict__ e, const float* __restrict__ mask,
    const float* __restrict__ cov,
    float* __restrict__ attn, float* __restrict__ covnew, float* __restrict__ ctx)
{
    __shared__ float sm[4], sps[4], spms[4];
    const int b = blockIdx.x, tid = threadIdx.x;
    ctx[(b << 9) + tid] = 0.f;
    ctx[(b << 9) + 256 + tid] = 0.f;

    float vals[2], msk[2];
    float m = -3.0e38f;
#pragma unroll
    for (int it = 0; it < 2; ++it) {
        const int s = tid + (it << 8);
        float mk = 0.f, v = -3.0e38f;
        if (s < 400) {
            mk = mask[b * 400 + s];
            v = (mk > 0.f) ? e[b * 400 + s] : -1.0e9f;
        }
        vals[it] = v; msk[it] = mk;
        m = fmaxf(m, v);
    }
#pragma unroll
    for (int off = 32; off > 0; off >>= 1) m = fmaxf(m, __shfl_down(m, off));
    if ((tid & 63) == 0) sm[tid >> 6] = m;
    __syncthreads();
    const float M = fmaxf(fmaxf(sm[0], sm[1]), fmaxf(sm[2], sm[3]));

    float p[2], sp = 0.f, spm = 0.f;
#pragma unroll
    for (int it = 0; it < 2; ++it) {
        const int s = tid + (it << 8);
        float pv = 0.f;
        if (s < 400) pv = __expf(vals[it] - M);
        p[it] = pv; sp += pv; spm += pv * msk[it];
    }
#pragma unroll
    for (int off = 32; off > 0; off >>= 1) {
        sp += __shfl_down(sp, off);
        spm += __shfl_down(spm, off);
    }
    if ((tid & 63) == 0) { sps[tid >> 6] = sp; spms[tid >> 6] = spm; }
    __syncthreads();
    const float SP = sps[0] + sps[1] + sps[2] + sps[3];
    const float SPM = spms[0] + spms[1] + spms[2] + spms[3];
    const float inv = 1.0f / (SPM + 1e-12f * SP);
#pragma unroll
    for (int it = 0; it < 2; ++it) {
        const int s = tid + (it << 8);
        if (s < 400) {
            const float a = p[it] * msk[it] * inv;
            attn[b * 400 + s] = a;
            covnew[b * 400 + s] = cov[b * 400 + s] + a;
        }
    }
}

// ctx[b,h] += sum over an s-chunk of attn[b,s]*states[b,s,h]; 4 chunks per b
__global__ __launch_bounds__(256) void ctx_kernel(
    const float* __restrict__ attn, const float* __restrict__ states,
    float* __restrict__ ctx)
{
    const int bx = blockIdx.x;  // 512
    const int b = bx >> 2, chunk = bx & 3;
    const int tid = threadIdx.x;
    const int c = tid & 127;
    const int sh = tid >> 7;
    const int s0 = chunk * 100 + sh;
    const float* base = states + (long)b * 400 * 512;
    float4 acc = make_float4(0.f, 0.f, 0.f, 0.f);
    for (int i = 0; i < 50; ++i) {
        const int s = s0 + (i << 1);
        const float a = attn[b * 400 + s];
        const float4 st = *(const float4*)(base + (long)s * 512 + (c << 2));
        acc.x = fmaf(a, st.x, acc.x);
        acc.y = fmaf(a, st.y, acc.y);
        acc.z = fmaf(a, st.z, acc.z);
        acc.w = fmaf(a, st.w, acc.w);
    }
    float* cp = ctx + (b << 9) + (c << 2);
    atomicAdd(cp + 0, acc.x);
    atomicAdd(cp + 1, acc.y);
    atomicAdd(cp + 2, acc.z);
    atomicAdd(cp + 3, acc.w);
}

// final[b, v<V] = p_gen*softmax(logits); final[b, V..VEXT) = 0.
// Merges the nblk per-tile row-stat partials; computes p_gen from the fused
// accumulator; block (0,b) writes o_pgen.
__global__ __launch_bounds__(256) void final_write(
    const float* __restrict__ logits, const float* __restrict__ pm,
    const float* __restrict__ ps, const float* __restrict__ pgen_acc,
    const float* __restrict__ bpg, float* __restrict__ final,
    float* __restrict__ o_pgen, int nblk)
{
    __shared__ float sred[4];
    __shared__ float sM, sS;
    const int b = blockIdx.y;
    const int tid = threadIdx.x;
    const float* pmb = pm + (long)b * nblk;
    const float* psb = ps + (long)b * nblk;

    float m = -3.0e38f;
    for (int i = tid; i < nblk; i += 256) m = fmaxf(m, pmb[i]);
#pragma unroll
    for (int off = 32; off > 0; off >>= 1) m = fmaxf(m, __shfl_down(m, off));
    if ((tid & 63) == 0) sred[tid >> 6] = m;
    __syncthreads();
    if (tid == 0) sM = fmaxf(fmaxf(sred[0], sred[1]), fmaxf(sred[2], sred[3]));
    __syncthreads();
    const float M = sM;

    float s = 0.f;
    for (int i = tid; i < nblk; i += 256) s += psb[i] * __expf(pmb[i] - M);
#pragma unroll
    for (int off = 32; off > 0; off >>= 1) s += __shfl_down(s, off);
    if ((tid & 63) == 0) sred[tid >> 6] = s;
    __syncthreads();
    if (tid == 0) sS = sred[0] + sred[1] + sred[2] + sred[3];
    __syncthreads();
    const float S = sS;

    const float pg = sigmoid_f(pgen_acc[b] + bpg[0]);
    if (blockIdx.x == 0 && tid == 0) o_pgen[b] = pg;

    const int v0 = (blockIdx.x * 256 + tid) << 2;
    if (v0 >= VX_) return;
    const float sc = pg / S;
    const float* row = logits + (long)b * V_;
    float* out = final + (long)b * VX_ + v0;
#pragma unroll
    for (int j = 0; j < 4; ++j) {
        const int v = v0 + j;
        if (v < VX_) out[j] = (v < V_) ? __expf(row[v] - M) * sc : 0.f;
    }
}

// scatter-add copy distribution
__global__ __launch_bounds__(256) void scatter_kernel(
    const int* __restrict__ ids, const float* __restrict__ attn,
    const float* __restrict__ pgen, float* __restrict__ final)
{
    const int s = blockIdx.x * 256 + threadIdx.x;
    const int b = blockIdx.y;
    if (s < 400) {
        const float v = (1.0f - pgen[b]) * attn[b * 400 + s];
        atomicAdd(final + (long)b * VX_ + ids[b * 400 + s], v);
    }
}

extern "C" void kernel_launch(void* const* d_in, const int* in_sizes, int n_in,
                              void* d_out, int out_size, void* d_ws, size_t ws_size,
                              hipStream_t stream)
{
    const float* input_emb  = (const float*)d_in[0];
    const float* input_feed = (const float*)d_in[1];
    const float* hidden     = (const float*)d_in[2];
    const float* context    = (const float*)d_in[3];
    const float* states     = (const float*)d_in[4];
    const float* sfeat      = (const float*)d_in[5];
    const float* mask       = (const float*)d_in[6];
    const float* cov        = (const float*)d_in[7];
    const int*   src_ids    = (const int*)d_in[8];
    const float* W_ic  = (const float*)d_in[9];
    const float* b_ic  = (const float*)d_in[10];
    const float* W_ih  = (const float*)d_in[11];
    const float* W_hh  = (const float*)d_in[12];
    const float* b_ih  = (const float*)d_in[13];
    const float* b_hh  = (const float*)d_in[14];
    const float* W_dec = (const float*)d_in[15];
    const float* b_att = (const float*)d_in[16];
    const float* v_att = (const float*)d_in[17];
    const float* w_c   = (const float*)d_in[18];
    const float* W_out = (const float*)d_in[19];
    const float* b_out = (const float*)d_in[20];
    const float* W_pg  = (const float*)d_in[21];
    const float* b_pg  = (const float*)d_in[22];
    const float* W_v   = (const float*)d_in[23];
    const float* b_v   = (const float*)d_in[24];

    float* out = (float*)d_out;
    float* o_final = out + OFF_FINAL;
    float* o_pgen  = out + OFF_PGEN;
    float* o_attn  = out + OFF_ATTN;
    float* o_cov   = out + OFF_COV;
    float* o_h1    = out + OFF_H1;
    float* o_c1    = out + OFF_C1;
    float* o_dec   = out + OFF_DEC;

    // ws layout (floats). [0, 393344) is the zeroed split-K accumulation region.
    float* ws = (float*)d_ws;
    float* w_x      = ws;            // 65536   (128x512)
    float* w_decfea = ws + 65536;    // 65536   (128x512)
    float* w_gates  = ws + 131072;   // 262144  (128x2048)
    float* w_pga    = ws + 393216;   // 128
    float* w_e      = ws + 393344;   // 51200   (128x400)
    float* w_ctx    = ws + 444544;   // 65536   (128x512)
    float* w_logits = ws + 510080;   // 6432896 (128x50257)
    float* w_pm     = ws + 6942976;  // 50304   (128x393)
    float* w_ps     = ws + 7043584;  // 50304   (128x393)

    const dim3 blk(256);
    // zero split-K accumulators (w_x, w_decfea, w_gates, w_pga contiguous) + o_dec
    zero_ws<<<385, blk, 0, stream>>>((float4*)ws, (float4*)o_dec);
    // x = [emb, feed] @ W_ic^T + b_ic   (split-K: 8 n-tiles x 8 chunks)
    gemm_mfma<4><<<dim3(8, 8), blk, 0, stream>>>(
        input_emb, W_ic, 1024, 0, input_feed, W_ic, 1024, 512,
        b_ic, w_x, 512, nullptr, nullptr);
    // gates = x @ W_ih^T + h0 @ W_hh^T + b_ih   (split-K: 32 n-tiles x 4 chunks)
    gemm_mfma<4><<<dim3(32, 4), blk, 0, stream>>>(
        w_x, W_ih, 512, 0, hidden, W_hh, 512, 0,
        b_ih, w_gates, 2048, nullptr, nullptr);
    // LSTM cell (adds b_hh) -> h1, c1
    lstm_cell<<<256, blk, 0, stream>>>(w_gates, b_hh, context, o_h1, o_c1);
    // dec_fea = h1 @ W_dec^T + b_att   (split-K: 8 x 4)
    gemm_mfma<4><<<dim3(8, 4), blk, 0, stream>>>(
        o_h1, W_dec, 512, 0, nullptr, nullptr, 0, 0,
        b_att, w_decfea, 512, nullptr, nullptr);
    // attention
    attn_scores<<<12800, blk, 0, stream>>>(sfeat, w_decfea, cov, w_c, v_att, w_e);
    attn_softmax<<<128, blk, 0, stream>>>(w_e, mask, cov, o_attn, o_cov, w_ctx);
    ctx_kernel<<<512, blk, 0, stream>>>(o_attn, states, w_ctx);
    // dec_out = [h1, ctx] @ W_out^T + b_out   (split-K 8 x 8, fused p_gen dot)
    gemm_mfma<4><<<dim3(8, 8), blk, 0, stream>>>(
        o_h1, W_out, 1024, 0, w_ctx, W_out, 1024, 512,
        b_out, o_dec, 512, W_pg, w_pga);
    // vocab logits + fused row softmax partials (393 x 2 blocks, W direct-to-reg)
    vocab_gemm<<<dim3(786), blk, 0, stream>>>(
        o_dec, W_v, b_v, w_logits, V_, w_pm, w_ps, 393);
    final_write<<<dim3(50, 128), blk, 0, stream>>>(w_logits, w_pm, w_ps, w_pga,
                                                   b_pg, o_final, o_pgen, 393);
    scatter_kernel<<<dim3(2, 128), blk, 0, stream>>>(src_ids, o_attn, o_pgen, o_final);
}

// Round 3
// 472.561 us; speedup vs baseline: 1.0145x; 1.0145x over previous
//
#include <hip/hip_runtime.h>
#include <hip/hip_bf16.h>

// Shapes
#define B_   128
#define S_   400
#define H_   512
#define V_   50257
#define VX_  50307

// Output offsets (floats, concatenated in return order)
#define OFF_FINAL 0
#define OFF_PGEN  6439296
#define OFF_ATTN  6439424
#define OFF_COV   6490624
#define OFF_H1    6541824
#define OFF_C1    6607360
#define OFF_DEC   6672896

typedef __attribute__((ext_vector_type(8))) short bf16x8;
typedef __attribute__((ext_vector_type(4))) float f32x4;

static __device__ __forceinline__ float sigmoid_f(float x) {
    return 1.0f / (1.0f + __expf(-x));
}
static __device__ __forceinline__ float tanh_f(float x) {
    return 1.0f - 2.0f / (__expf(2.0f * x) + 1.0f);
}
// f32x2 -> packed bf16x2 (RNE) — v_cvt_pk_bf16_f32 on gfx950
static __device__ __forceinline__ unsigned int pk2(float x, float y) {
    union { __hip_bfloat162 h; unsigned int u; } cv;
    cv.h = __float22bfloat162_rn(make_float2(x, y));
    return cv.u;
}

// Zero the split-K accumulation region of ws (w_x, w_decfea, w_gates, w_pga
// laid out contiguously: 393344 floats = 98336 float4) + o_dec (16384 float4).
__global__ __launch_bounds__(256) void zero_ws(
    float4* __restrict__ ws4, float4* __restrict__ dec4)
{
    const int i = blockIdx.x * 256 + threadIdx.x;
    const float4 z = make_float4(0.f, 0.f, 0.f, 0.f);
    if (i < 98336) ws4[i] = z;
    if (i < 16384) dec4[i] = z;
}

// ---------------------------------------------------------------------------
// Generic small GEMM: C[128 x N] (+)= A1@W1^T (+ A2@W2^T) + bias1.
// Split-K via grid.y with atomic epilogue; optional fused p_gen dot.
// ---------------------------------------------------------------------------
template <int NT>
__global__ __launch_bounds__(256) void gemm_mfma(
    const float* __restrict__ A1, const float* __restrict__ W1, int ldw1, int kwo1,
    const float* __restrict__ A2, const float* __restrict__ W2, int ldw2, int kwo2,
    const float* __restrict__ bias1,
    float* __restrict__ C, int N,
    const float* __restrict__ wpg, float* __restrict__ pgen_acc)
{
    __shared__ __align__(16) unsigned short As[128 * 40];
    __shared__ __align__(16) unsigned short Ws[NT * 16 * 40];
    const int tid  = threadIdx.x;
    const int bn0  = blockIdx.x * (NT * 16);
    const int lane = tid & 63;
    const int wv   = tid >> 6;
    const int quad = lane >> 4;
    const int col  = lane & 15;

    f32x4 acc[2][NT];
#pragma unroll
    for (int i = 0; i < 2; ++i)
#pragma unroll
        for (int j = 0; j < NT; ++j) acc[i][j] = (f32x4){0.f, 0.f, 0.f, 0.f};

    const int ar = tid >> 1;
    const int ac = (tid & 1) << 4;
    const int wr = (NT == 8) ? (tid >> 1) : (tid >> 2);
    const int wc = (NT == 8) ? ((tid & 1) << 4) : ((tid & 3) << 3);
    const int wrg = (bn0 + wr < N) ? (bn0 + wr) : (N - 1);

    const int Ktot = (A2 != nullptr) ? 1024 : 512;
    const int KC   = Ktot / gridDim.y;
    const int kg0  = blockIdx.y * KC;
    const int nsteps = KC >> 5;

    const float* ApB[2];
    const float* WpB[2];
    ApB[0] = A1 + (long)ar * 512 + ac;
    WpB[0] = W1 + (long)wrg * ldw1 + kwo1 + wc;
    ApB[1] = A2 ? (A2 + (long)ar * 512 + ac) : ApB[0];
    WpB[1] = W2 ? (W2 + (long)wrg * ldw2 + kwo2 + wc) : WpB[0];

    float4 aC[4], wC[NT / 2], aN[4], wN[NT / 2];

    auto fetch = [&](int s, float4* a, float4* w) {
        const int kg = kg0 + (s << 5);
        const int ph = kg >> 9;
        const int k0 = kg & 511;
        const float* Ap = ApB[ph] + k0;
        const float* Wp = WpB[ph] + k0;
#pragma unroll
        for (int i = 0; i < 4; ++i) a[i] = *(const float4*)(Ap + i * 4);
#pragma unroll
        for (int i = 0; i < NT / 2; ++i) w[i] = *(const float4*)(Wp + i * 4);
    };

    fetch(0, aC, wC);
    for (int s = 0; s < nsteps; ++s) {
        __syncthreads();
        uint4* apd = (uint4*)&As[ar * 40 + ac];
        apd[0] = make_uint4(pk2(aC[0].x, aC[0].y), pk2(aC[0].z, aC[0].w),
                            pk2(aC[1].x, aC[1].y), pk2(aC[1].z, aC[1].w));
        apd[1] = make_uint4(pk2(aC[2].x, aC[2].y), pk2(aC[2].z, aC[2].w),
                            pk2(aC[3].x, aC[3].y), pk2(aC[3].z, aC[3].w));
        uint4* wpd = (uint4*)&Ws[wr * 40 + wc];
        wpd[0] = make_uint4(pk2(wC[0].x, wC[0].y), pk2(wC[0].z, wC[0].w),
                            pk2(wC[1].x, wC[1].y), pk2(wC[1].z, wC[1].w));
        if (NT == 8)
            wpd[1] = make_uint4(pk2(wC[2].x, wC[2].y), pk2(wC[2].z, wC[2].w),
                                pk2(wC[3].x, wC[3].y), pk2(wC[3].z, wC[3].w));
        __syncthreads();

        if (s + 1 < nsteps) fetch(s + 1, aN, wN);

        const bf16x8 aF0 = *(const bf16x8*)&As[(wv * 32 + col) * 40 + quad * 8];
        const bf16x8 aF1 = *(const bf16x8*)&As[(wv * 32 + 16 + col) * 40 + quad * 8];
#pragma unroll
        for (int ni = 0; ni < NT; ++ni) {
            const bf16x8 bF = *(const bf16x8*)&Ws[(ni * 16 + col) * 40 + quad * 8];
            acc[0][ni] = __builtin_amdgcn_mfma_f32_16x16x32_bf16(aF0, bF, acc[0][ni], 0, 0, 0);
            acc[1][ni] = __builtin_amdgcn_mfma_f32_16x16x32_bf16(aF1, bF, acc[1][ni], 0, 0, 0);
        }
#pragma unroll
        for (int i = 0; i < 4; ++i) aC[i] = aN[i];
#pragma unroll
        for (int i = 0; i < NT / 2; ++i) wC[i] = wN[i];
    }

    const bool split = (gridDim.y > 1);
    const bool addb  = (!split) || (blockIdx.y == 0);

    float pgp[2][4];
#pragma unroll
    for (int i = 0; i < 2; ++i)
#pragma unroll
        for (int r = 0; r < 4; ++r) pgp[i][r] = 0.f;

#pragma unroll
    for (int mi = 0; mi < 2; ++mi) {
#pragma unroll
        for (int ni = 0; ni < NT; ++ni) {
            const int n = bn0 + ni * 16 + col;
            if (n < N) {
                const float bv = addb ? bias1[n] : 0.f;
                const float wpv = wpg ? wpg[n] : 0.f;
#pragma unroll
                for (int r = 0; r < 4; ++r) {
                    const int m = wv * 32 + mi * 16 + quad * 4 + r;
                    const float v = acc[mi][ni][r] + bv;
                    if (split) atomicAdd(&C[(long)m * N + n], v);
                    else       C[(long)m * N + n] = v;
                    pgp[mi][r] += v * wpv;
                }
            }
        }
    }
    if (wpg) {
#pragma unroll
        for (int mi = 0; mi < 2; ++mi)
#pragma unroll
            for (int r = 0; r < 4; ++r) {
                float v = pgp[mi][r];
                v += __shfl_xor(v, 1); v += __shfl_xor(v, 2);
                v += __shfl_xor(v, 4); v += __shfl_xor(v, 8);
                if (col == 0) {
                    const int m = wv * 32 + mi * 16 + quad * 4 + r;
                    atomicAdd(&pgen_acc[m], v);
                }
            }
    }
}

// ---------------------------------------------------------------------------
// Pack A (= dec_out, 128x512 f32) into MFMA-fragment-ordered bf16:
// unit u = ((sl*8+mt)*4+q)*16+c  holds A[mt*16+c][sl*32+q*8 .. +8] (16B).
// Compute-phase loads of a (sl,mt) fragment group are then 1KB-contiguous.
// ---------------------------------------------------------------------------
__global__ __launch_bounds__(256) void pack_a(
    const float* __restrict__ A, unsigned short* __restrict__ Apk)
{
    const int u  = blockIdx.x * 256 + threadIdx.x;  // 8192 units
    const int c  = u & 15;
    const int q  = (u >> 4) & 3;
    const int mt = (u >> 6) & 7;
    const int sl = u >> 9;
    const float* src = A + (long)(mt * 16 + c) * 512 + sl * 32 + q * 8;
    const float4 x = *(const float4*)src;
    const float4 y = *(const float4*)(src + 4);
    *(uint4*)(Apk + (long)u * 8) = make_uint4(pk2(x.x, x.y), pk2(x.z, x.w),
                                              pk2(y.x, y.y), pk2(y.z, y.w));
}

// ---------------------------------------------------------------------------
// Vocab GEMM v3: C[128 x N] = A @ W^T + bias, fused row-softmax partials.
// Block = 64 output cols x all 128 rows (W panel read ONCE, wave-contiguous):
// stage phase reads one full 2KB W row per wave-instruction (perfect DRAM
// streaming) into 64KB XOR-swizzled bf16 LDS; compute phase: 16 k-slices,
// B-frag from LDS, A-frags double-buffered from packed L2-resident Apk,
// 8 MFMA per slice per wave, no per-slice barriers.
// ---------------------------------------------------------------------------
__global__ __launch_bounds__(256, 2) void vocab_gemm(
    const unsigned short* __restrict__ Apk, const float* __restrict__ W,
    const float* __restrict__ bias, float* __restrict__ C, int N,
    float* __restrict__ pm, float* __restrict__ ps, int nbn)
{
    __shared__ __align__(16) unsigned short Ws[64 * 512];  // 64 KB
    const int tid  = threadIdx.x;
    const int lane = tid & 63;
    const int w    = tid >> 6;
    const int quad = lane >> 4;
    const int c    = lane & 15;
    const int nb   = blockIdx.x;

    // ---- stage W[nb*64 .. +64)[0..512) -> bf16 LDS, swizzled (16B gran) ----
    // iter i: wave w reads local row i*4+w fully (lane covers 32B) -> 2KB/instr
#pragma unroll
    for (int i = 0; i < 16; ++i) {
        const int r  = i * 4 + w;                       // local row 0..63
        const int rg = (nb * 64 + r < N) ? (nb * 64 + r) : (N - 1);
        const int k  = lane << 3;                       // 0..504 floats
        const float* src = W + (long)rg * 512 + k;
        const float4 x = *(const float4*)src;
        const float4 y = *(const float4*)(src + 4);
        const int a16 = (r << 6) + (lane ^ (r & 7));    // 16B-unit index
        *(uint4*)&Ws[a16 << 3] = make_uint4(pk2(x.x, x.y), pk2(x.z, x.w),
                                            pk2(y.x, y.y), pk2(y.z, y.w));
    }

    f32x4 acc[8];
#pragma unroll
    for (int mt = 0; mt < 8; ++mt) acc[mt] = (f32x4){0.f, 0.f, 0.f, 0.f};

    bf16x8 aA[8], aB[8];
    auto loadA = [&](int sl, bf16x8* dst) {
#pragma unroll
        for (int mt = 0; mt < 8; ++mt) {
            const long u = (((long)(sl * 8 + mt) * 4 + quad) << 4) + c;
            dst[mt] = *(const bf16x8*)(Apk + u * 8);
        }
    };
    loadA(0, aA);           // overlap slice-0 A loads with the barrier
    __syncthreads();

#pragma unroll
    for (int sl = 0; sl < 16; ++sl) {
        bf16x8* cur = (sl & 1) ? aB : aA;
        bf16x8* nxt = (sl & 1) ? aA : aB;
        if (sl + 1 < 16) loadA(sl + 1, nxt);
        const int a16 = ((w * 16 + c) << 6) + (((sl << 2) + quad) ^ (c & 7));
        const bf16x8 bF = *(const bf16x8*)&Ws[a16 << 3];
#pragma unroll
        for (int mt = 0; mt < 8; ++mt)
            acc[mt] = __builtin_amdgcn_mfma_f32_16x16x32_bf16(cur[mt], bF, acc[mt], 0, 0, 0);
    }

    // ---- epilogue: store logits + per-block row stats (max, exp-sum) ----
    __syncthreads();                 // all Ws reads done; reuse as scratch
    float* redM = (float*)Ws;        // [128][4]
    float* redS = (float*)Ws + 512;  // [128][4]
    const int n  = nb * 64 + w * 16 + c;
    const bool ok = (n < N);
    const float bv = bias[ok ? n : (N - 1)];
#pragma unroll
    for (int mt = 0; mt < 8; ++mt) {
#pragma unroll
        for (int r = 0; r < 4; ++r) {
            const float v = acc[mt][r] + bv;
            const int m = mt * 16 + quad * 4 + r;
            if (ok) C[(long)m * N + n] = v;
            float mx = ok ? v : -3.0e38f;
            mx = fmaxf(mx, __shfl_xor(mx, 1));
            mx = fmaxf(mx, __shfl_xor(mx, 2));
            mx = fmaxf(mx, __shfl_xor(mx, 4));
            mx = fmaxf(mx, __shfl_xor(mx, 8));
            float sv = ok ? __expf(v - mx) : 0.f;
            sv += __shfl_xor(sv, 1); sv += __shfl_xor(sv, 2);
            sv += __shfl_xor(sv, 4); sv += __shfl_xor(sv, 8);
            if (c == 0) {
                redM[m * 4 + w] = mx;
                redS[m * 4 + w] = sv;
            }
        }
    }
    __syncthreads();
    if (tid < 128) {
        float M = -3.0e38f;
#pragma unroll
        for (int j = 0; j < 4; ++j) M = fmaxf(M, redM[tid * 4 + j]);
        float S = 0.f;
#pragma unroll
        for (int j = 0; j < 4; ++j) S += redS[tid * 4 + j] * __expf(redM[tid * 4 + j] - M);
        pm[(long)tid * nbn + nb] = M;
        ps[(long)tid * nbn + nb] = S;
    }
}

// Elementwise LSTM cell over the accumulated gates buffer [128 x 2048]
// (i,f,g,o column-stacked). b_ih was added by the gates GEMM; add b_hh here.
__global__ __launch_bounds__(256) void lstm_cell(
    const float* __restrict__ gates, const float* __restrict__ bhh,
    const float* __restrict__ c0,
    float* __restrict__ h1, float* __restrict__ c1)
{
    const int idx = blockIdx.x * 256 + threadIdx.x;  // 65536 = 128*512
    const int m = idx >> 9;
    const int h = idx & 511;
    const float* g = gates + (long)m * 2048;
    const float iv = sigmoid_f(g[h]        + bhh[h]);
    const float fv = sigmoid_f(g[512 + h]  + bhh[512 + h]);
    const float gv = tanh_f   (g[1024 + h] + bhh[1024 + h]);
    const float ov = sigmoid_f(g[1536 + h] + bhh[1536 + h]);
    const float c = fv * c0[idx] + iv * gv;
    c1[idx] = c;
    h1[idx] = ov * tanh_f(c);
}

// e[b,s] = sum_h tanh(sf[b,s,h] + dec_fea[b,h] + wc*cov[b,s]) * v_att[h]
__global__ __launch_bounds__(256) void attn_scores(
    const float* __restrict__ sfeat, const float* __restrict__ decfea,
    const float* __restrict__ cov, const float* __restrict__ wc,
    const float* __restrict__ vatt, float* __restrict__ e)
{
    const int lane = threadIdx.x & 63;
    const int pair = blockIdx.x * 4 + (threadIdx.x >> 6);  // b*400+s
    const int b = pair / 400;
    const float cc = wc[0] * cov[pair];
    const float* sp = sfeat + ((long)pair << 9) + (lane << 3);
    const float* dp = decfea + (b << 9) + (lane << 3);
    const float* vp = vatt + (lane << 3);
    const float4 s0 = *(const float4*)sp, s1 = *(const float4*)(sp + 4);
    const float4 d0 = *(const float4*)dp, d1 = *(const float4*)(dp + 4);
    const float4 v0 = *(const float4*)vp, v1 = *(const float4*)(vp + 4);
    float acc = tanh_f(s0.x + d0.x + cc) * v0.x
              + tanh_f(s0.y + d0.y + cc) * v0.y
              + tanh_f(s0.z + d0.z + cc) * v0.z
              + tanh_f(s0.w + d0.w + cc) * v0.w
              + tanh_f(s1.x + d1.x + cc) * v1.x
              + tanh_f(s1.y + d1.y + cc) * v1.y
              + tanh_f(s1.z + d1.z + cc) * v1.z
              + tanh_f(s1.w + d1.w + cc) * v1.w;
#pragma unroll
    for (int off = 32; off > 0; off >>= 1) acc += __shfl_down(acc, off);
    if (lane == 0) e[pair] = acc;
}

// Masked softmax over S per batch row + coverage update; also zeroes ctx accum.
__global__ __launch_bounds__(256) void attn_softmax(
    const float* __restrict__ e, const float* __restrict__ mask,
    const float* __restrict__ cov,
    float* __restrict__ attn, float* __restrict__ covnew, float* __restrict__ ctx)
{
    __shared__ float sm[4], sps[4], spms[4];
    const int b = blockIdx.x, tid = threadIdx.x;
    ctx[(b << 9) + tid] = 0.f;
    ctx[(b << 9) + 256 + tid] = 0.f;

    float vals[2], msk[2];
    float m = -3.0e38f;
#pragma unroll
    for (int it = 0; it < 2; ++it) {
        const int s = tid + (it << 8);
        float mk = 0.f, v = -3.0e38f;
        if (s < 400) {
            mk = mask[b * 400 + s];
            v = (mk > 0.f) ? e[b * 400 + s] : -1.0e9f;
        }
        vals[it] = v; msk[it] = mk;
        m = fmaxf(m, v);
    }
#pragma unroll
    for (int off = 32; off > 0; off >>= 1) m = fmaxf(m, __shfl_down(m, off));
    if ((tid & 63) == 0) sm[tid >> 6] = m;
    __syncthreads();
    const float M = fmaxf(fmaxf(sm[0], sm[1]), fmaxf(sm[2], sm[3]));

    float p[2], sp = 0.f, spm = 0.f;
#pragma unroll
    for (int it = 0; it < 2; ++it) {
        const int s = tid + (it << 8);
        float pv = 0.f;
        if (s < 400) pv = __expf(vals[it] - M);
        p[it] = pv; sp += pv; spm += pv * msk[it];
    }
#pragma unroll
    for (int off = 32; off > 0; off >>= 1) {
        sp += __shfl_down(sp, off);
        spm += __shfl_down(spm, off);
    }
    if ((tid & 63) == 0) { sps[tid >> 6] = sp; spms[tid >> 6] = spm; }
    __syncthreads();
    const float SP = sps[0] + sps[1] + sps[2] + sps[3];
    const float SPM = spms[0] + spms[1] + spms[2] + spms[3];
    const float inv = 1.0f / (SPM + 1e-12f * SP);
#pragma unroll
    for (int it = 0; it < 2; ++it) {
        const int s = tid + (it << 8);
        if (s < 400) {
            const float a = p[it] * msk[it] * inv;
            attn[b * 400 + s] = a;
            covnew[b * 400 + s] = cov[b * 400 + s] + a;
        }
    }
}

// ctx[b,h] += sum over an s-chunk of attn[b,s]*states[b,s,h]; 4 chunks per b
__global__ __launch_bounds__(256) void ctx_kernel(
    const float* __restrict__ attn, const float* __restrict__ states,
    float* __restrict__ ctx)
{
    const int bx = blockIdx.x;  // 512
    const int b = bx >> 2, chunk = bx & 3;
    const int tid = threadIdx.x;
    const int c = tid & 127;
    const int sh = tid >> 7;
    const int s0 = chunk * 100 + sh;
    const float* base = states + (long)b * 400 * 512;
    float4 acc = make_float4(0.f, 0.f, 0.f, 0.f);
    for (int i = 0; i < 50; ++i) {
        const int s = s0 + (i << 1);
        const float a = attn[b * 400 + s];
        const float4 st = *(const float4*)(base + (long)s * 512 + (c << 2));
        acc.x = fmaf(a, st.x, acc.x);
        acc.y = fmaf(a, st.y, acc.y);
        acc.z = fmaf(a, st.z, acc.z);
        acc.w = fmaf(a, st.w, acc.w);
    }
    float* cp = ctx + (b << 9) + (c << 2);
    atomicAdd(cp + 0, acc.x);
    atomicAdd(cp + 1, acc.y);
    atomicAdd(cp + 2, acc.z);
    atomicAdd(cp + 3, acc.w);
}

// final[b, v<V] = p_gen*softmax(logits); final[b, V..VEXT) = 0.
// Merges the nblk per-tile row-stat partials; computes p_gen from the fused
// accumulator; block (0,b) writes o_pgen.
__global__ __launch_bounds__(256) void final_write(
    const float* __restrict__ logits, const float* __restrict__ pm,
    const float* __restrict__ ps, const float* __restrict__ pgen_acc,
    const float* __restrict__ bpg, float* __restrict__ final,
    float* __restrict__ o_pgen, int nblk)
{
    __shared__ float sred[4];
    __shared__ float sM, sS;
    const int b = blockIdx.y;
    const int tid = threadIdx.x;
    const float* pmb = pm + (long)b * nblk;
    const float* psb = ps + (long)b * nblk;

    float m = -3.0e38f;
    for (int i = tid; i < nblk; i += 256) m = fmaxf(m, pmb[i]);
#pragma unroll
    for (int off = 32; off > 0; off >>= 1) m = fmaxf(m, __shfl_down(m, off));
    if ((tid & 63) == 0) sred[tid >> 6] = m;
    __syncthreads();
    if (tid == 0) sM = fmaxf(fmaxf(sred[0], sred[1]), fmaxf(sred[2], sred[3]));
    __syncthreads();
    const float M = sM;

    float s = 0.f;
    for (int i = tid; i < nblk; i += 256) s += psb[i] * __expf(pmb[i] - M);
#pragma unroll
    for (int off = 32; off > 0; off >>= 1) s += __shfl_down(s, off);
    if ((tid & 63) == 0) sred[tid >> 6] = s;
    __syncthreads();
    if (tid == 0) sS = sred[0] + sred[1] + sred[2] + sred[3];
    __syncthreads();
    const float S = sS;

    const float pg = sigmoid_f(pgen_acc[b] + bpg[0]);
    if (blockIdx.x == 0 && tid == 0) o_pgen[b] = pg;

    const int v0 = (blockIdx.x * 256 + tid) << 2;
    if (v0 >= VX_) return;
    const float sc = pg / S;
    const float* row = logits + (long)b * V_;
    float* out = final + (long)b * VX_ + v0;
#pragma unroll
    for (int j = 0; j < 4; ++j) {
        const int v = v0 + j;
        if (v < VX_) out[j] = (v < V_) ? __expf(row[v] - M) * sc : 0.f;
    }
}

// scatter-add copy distribution
__global__ __launch_bounds__(256) void scatter_kernel(
    const int* __restrict__ ids, const float* __restrict__ attn,
    const float* __restrict__ pgen, float* __restrict__ final)
{
    const int s = blockIdx.x * 256 + threadIdx.x;
    const int b = blockIdx.y;
    if (s < 400) {
        const float v = (1.0f - pgen[b]) * attn[b * 400 + s];
        atomicAdd(final + (long)b * VX_ + ids[b * 400 + s], v);
    }
}

extern "C" void kernel_launch(void* const* d_in, const int* in_sizes, int n_in,
                              void* d_out, int out_size, void* d_ws, size_t ws_size,
                              hipStream_t stream)
{
    const float* input_emb  = (const float*)d_in[0];
    const float* input_feed = (const float*)d_in[1];
    const float* hidden     = (const float*)d_in[2];
    const float* context    = (const float*)d_in[3];
    const float* states     = (const float*)d_in[4];
    const float* sfeat      = (const float*)d_in[5];
    const float* mask       = (const float*)d_in[6];
    const float* cov        = (const float*)d_in[7];
    const int*   src_ids    = (const int*)d_in[8];
    const float* W_ic  = (const float*)d_in[9];
    const float* b_ic  = (const float*)d_in[10];
    const float* W_ih  = (const float*)d_in[11];
    const float* W_hh  = (const float*)d_in[12];
    const float* b_ih  = (const float*)d_in[13];
    const float* b_hh  = (const float*)d_in[14];
    const float* W_dec = (const float*)d_in[15];
    const float* b_att = (const float*)d_in[16];
    const float* v_att = (const float*)d_in[17];
    const float* w_c   = (const float*)d_in[18];
    const float* W_out = (const float*)d_in[19];
    const float* b_out = (const float*)d_in[20];
    const float* W_pg  = (const float*)d_in[21];
    const float* b_pg  = (const float*)d_in[22];
    const float* W_v   = (const float*)d_in[23];
    const float* b_v   = (const float*)d_in[24];

    float* out = (float*)d_out;
    float* o_final = out + OFF_FINAL;
    float* o_pgen  = out + OFF_PGEN;
    float* o_attn  = out + OFF_ATTN;
    float* o_cov   = out + OFF_COV;
    float* o_h1    = out + OFF_H1;
    float* o_c1    = out + OFF_C1;
    float* o_dec   = out + OFF_DEC;

    // ws layout (floats). [0, 393344) is the zeroed split-K accumulation region.
    float* ws = (float*)d_ws;
    float* w_x      = ws;            // 65536   (128x512)
    float* w_decfea = ws + 65536;    // 65536   (128x512)
    float* w_gates  = ws + 131072;   // 262144  (128x2048); reused for Apk after LSTM
    float* w_pga    = ws + 393216;   // 128
    float* w_e      = ws + 393344;   // 51200   (128x400)
    float* w_ctx    = ws + 444544;   // 65536   (128x512)
    float* w_logits = ws + 510080;   // 6432896 (128x50257)
    float* w_pm     = ws + 6942976;  // 100608  (128x786)
    float* w_ps     = ws + 7043584;  // 100608  (128x786)
    unsigned short* w_apk = (unsigned short*)w_gates;  // 128KB packed A

    const dim3 blk(256);
    // zero split-K accumulators (w_x, w_decfea, w_gates, w_pga contiguous) + o_dec
    zero_ws<<<385, blk, 0, stream>>>((float4*)ws, (float4*)o_dec);
    // x = [emb, feed] @ W_ic^T + b_ic   (split-K: 8 n-tiles x 8 chunks)
    gemm_mfma<4><<<dim3(8, 8), blk, 0, stream>>>(
        input_emb, W_ic, 1024, 0, input_feed, W_ic, 1024, 512,
        b_ic, w_x, 512, nullptr, nullptr);
    // gates = x @ W_ih^T + h0 @ W_hh^T + b_ih   (split-K: 32 n-tiles x 4 chunks)
    gemm_mfma<4><<<dim3(32, 4), blk, 0, stream>>>(
        w_x, W_ih, 512, 0, hidden, W_hh, 512, 0,
        b_ih, w_gates, 2048, nullptr, nullptr);
    // LSTM cell (adds b_hh) -> h1, c1
    lstm_cell<<<256, blk, 0, stream>>>(w_gates, b_hh, context, o_h1, o_c1);
    // dec_fea = h1 @ W_dec^T + b_att   (split-K: 8 x 4)
    gemm_mfma<4><<<dim3(8, 4), blk, 0, stream>>>(
        o_h1, W_dec, 512, 0, nullptr, nullptr, 0, 0,
        b_att, w_decfea, 512, nullptr, nullptr);
    // attention
    attn_scores<<<12800, blk, 0, stream>>>(sfeat, w_decfea, cov, w_c, v_att, w_e);
    attn_softmax<<<128, blk, 0, stream>>>(w_e, mask, cov, o_attn, o_cov, w_ctx);
    ctx_kernel<<<512, blk, 0, stream>>>(o_attn, states, w_ctx);
    // dec_out = [h1, ctx] @ W_out^T + b_out   (split-K 8 x 8, fused p_gen dot)
    gemm_mfma<4><<<dim3(8, 8), blk, 0, stream>>>(
        o_h1, W_out, 1024, 0, w_ctx, W_out, 1024, 512,
        b_out, o_dec, 512, W_pg, w_pga);
    // pack dec_out into MFMA-fragment bf16 layout (L2-resident)
    pack_a<<<32, blk, 0, stream>>>(o_dec, w_apk);
    // vocab logits + fused row softmax partials (786 blocks, W wave-contiguous)
    vocab_gemm<<<786, blk, 0, stream>>>(
        w_apk, W_v, b_v, w_logits, V_, w_pm, w_ps, 786);
    final_write<<<dim3(50, 128), blk, 0, stream>>>(w_logits, w_pm, w_ps, w_pga,
                                                   b_pg, o_final, o_pgen, 786);
    scatter_kernel<<<dim3(2, 128), blk, 0, stream>>>(src_ids, o_attn, o_pgen, o_final);
}

// Round 4
// 446.711 us; speedup vs baseline: 1.0732x; 1.0579x over previous
//
#include <hip/hip_runtime.h>
#include <hip/hip_bf16.h>

// Shapes
#define B_   128
#define S_   400
#define H_   512
#define V_   50257
#define VX_  50307
#define NBN_ 1571   // ceil(V/32) vocab col-panels

// Output offsets (floats, concatenated in return order)
#define OFF_FINAL 0
#define OFF_PGEN  6439296
#define OFF_ATTN  6439424
#define OFF_COV   6490624
#define OFF_H1    6541824
#define OFF_C1    6607360
#define OFF_DEC   6672896

typedef __attribute__((ext_vector_type(8))) short bf16x8;
typedef __attribute__((ext_vector_type(4))) float f32x4;

static __device__ __forceinline__ float sigmoid_f(float x) {
    return 1.0f / (1.0f + __expf(-x));
}
static __device__ __forceinline__ float tanh_f(float x) {
    return 1.0f - 2.0f / (__expf(2.0f * x) + 1.0f);
}
// f32x2 -> packed bf16x2 (RNE) — v_cvt_pk_bf16_f32 on gfx950
static __device__ __forceinline__ unsigned int pk2(float x, float y) {
    union { __hip_bfloat162 h; unsigned int u; } cv;
    cv.h = __float22bfloat162_rn(make_float2(x, y));
    return cv.u;
}

// Zero split-K accumulators: ws[0, 393216) (w_x,w_decfea,w_gates = 98304
// float4), o_dec (16384 float4), and the relocated p_gen accumulator (32 f4).
__global__ __launch_bounds__(256) void zero_ws(
    float4* __restrict__ ws4, float4* __restrict__ dec4, float4* __restrict__ pga4)
{
    const int i = blockIdx.x * 256 + threadIdx.x;
    const float4 z = make_float4(0.f, 0.f, 0.f, 0.f);
    if (i < 98304) ws4[i] = z;
    if (i < 16384) dec4[i] = z;
    if (i < 32)    pga4[i] = z;
}

// ---------------------------------------------------------------------------
// Generic small GEMM: C[128 x N] (+)= A1@W1^T (+ A2@W2^T) + bias1.
// Split-K via grid.y with atomic epilogue; optional fused p_gen dot.
// ---------------------------------------------------------------------------
template <int NT>
__global__ __launch_bounds__(256) void gemm_mfma(
    const float* __restrict__ A1, const float* __restrict__ W1, int ldw1, int kwo1,
    const float* __restrict__ A2, const float* __restrict__ W2, int ldw2, int kwo2,
    const float* __restrict__ bias1,
    float* __restrict__ C, int N,
    const float* __restrict__ wpg, float* __restrict__ pgen_acc)
{
    __shared__ __align__(16) unsigned short As[128 * 40];
    __shared__ __align__(16) unsigned short Ws[NT * 16 * 40];
    const int tid  = threadIdx.x;
    const int bn0  = blockIdx.x * (NT * 16);
    const int lane = tid & 63;
    const int wv   = tid >> 6;
    const int quad = lane >> 4;
    const int col  = lane & 15;

    f32x4 acc[2][NT];
#pragma unroll
    for (int i = 0; i < 2; ++i)
#pragma unroll
        for (int j = 0; j < NT; ++j) acc[i][j] = (f32x4){0.f, 0.f, 0.f, 0.f};

    const int ar = tid >> 1;
    const int ac = (tid & 1) << 4;
    const int wr = (NT == 8) ? (tid >> 1) : (tid >> 2);
    const int wc = (NT == 8) ? ((tid & 1) << 4) : ((tid & 3) << 3);
    const int wrg = (bn0 + wr < N) ? (bn0 + wr) : (N - 1);

    const int Ktot = (A2 != nullptr) ? 1024 : 512;
    const int KC   = Ktot / gridDim.y;
    const int kg0  = blockIdx.y * KC;
    const int nsteps = KC >> 5;

    const float* ApB[2];
    const float* WpB[2];
    ApB[0] = A1 + (long)ar * 512 + ac;
    WpB[0] = W1 + (long)wrg * ldw1 + kwo1 + wc;
    ApB[1] = A2 ? (A2 + (long)ar * 512 + ac) : ApB[0];
    WpB[1] = W2 ? (W2 + (long)wrg * ldw2 + kwo2 + wc) : WpB[0];

    float4 aC[4], wC[NT / 2], aN[4], wN[NT / 2];

    auto fetch = [&](int s, float4* a, float4* w) {
        const int kg = kg0 + (s << 5);
        const int ph = kg >> 9;
        const int k0 = kg & 511;
        const float* Ap = ApB[ph] + k0;
        const float* Wp = WpB[ph] + k0;
#pragma unroll
        for (int i = 0; i < 4; ++i) a[i] = *(const float4*)(Ap + i * 4);
#pragma unroll
        for (int i = 0; i < NT / 2; ++i) w[i] = *(const float4*)(Wp + i * 4);
    };

    fetch(0, aC, wC);
    for (int s = 0; s < nsteps; ++s) {
        __syncthreads();
        uint4* apd = (uint4*)&As[ar * 40 + ac];
        apd[0] = make_uint4(pk2(aC[0].x, aC[0].y), pk2(aC[0].z, aC[0].w),
                            pk2(aC[1].x, aC[1].y), pk2(aC[1].z, aC[1].w));
        apd[1] = make_uint4(pk2(aC[2].x, aC[2].y), pk2(aC[2].z, aC[2].w),
                            pk2(aC[3].x, aC[3].y), pk2(aC[3].z, aC[3].w));
        uint4* wpd = (uint4*)&Ws[wr * 40 + wc];
        wpd[0] = make_uint4(pk2(wC[0].x, wC[0].y), pk2(wC[0].z, wC[0].w),
                            pk2(wC[1].x, wC[1].y), pk2(wC[1].z, wC[1].w));
        if (NT == 8)
            wpd[1] = make_uint4(pk2(wC[2].x, wC[2].y), pk2(wC[2].z, wC[2].w),
                                pk2(wC[3].x, wC[3].y), pk2(wC[3].z, wC[3].w));
        __syncthreads();

        if (s + 1 < nsteps) fetch(s + 1, aN, wN);

        const bf16x8 aF0 = *(const bf16x8*)&As[(wv * 32 + col) * 40 + quad * 8];
        const bf16x8 aF1 = *(const bf16x8*)&As[(wv * 32 + 16 + col) * 40 + quad * 8];
#pragma unroll
        for (int ni = 0; ni < NT; ++ni) {
            const bf16x8 bF = *(const bf16x8*)&Ws[(ni * 16 + col) * 40 + quad * 8];
            acc[0][ni] = __builtin_amdgcn_mfma_f32_16x16x32_bf16(aF0, bF, acc[0][ni], 0, 0, 0);
            acc[1][ni] = __builtin_amdgcn_mfma_f32_16x16x32_bf16(aF1, bF, acc[1][ni], 0, 0, 0);
        }
#pragma unroll
        for (int i = 0; i < 4; ++i) aC[i] = aN[i];
#pragma unroll
        for (int i = 0; i < NT / 2; ++i) wC[i] = wN[i];
    }

    const bool split = (gridDim.y > 1);
    const bool addb  = (!split) || (blockIdx.y == 0);

    float pgp[2][4];
#pragma unroll
    for (int i = 0; i < 2; ++i)
#pragma unroll
        for (int r = 0; r < 4; ++r) pgp[i][r] = 0.f;

#pragma unroll
    for (int mi = 0; mi < 2; ++mi) {
#pragma unroll
        for (int ni = 0; ni < NT; ++ni) {
            const int n = bn0 + ni * 16 + col;
            if (n < N) {
                const float bv = addb ? bias1[n] : 0.f;
                const float wpv = wpg ? wpg[n] : 0.f;
#pragma unroll
                for (int r = 0; r < 4; ++r) {
                    const int m = wv * 32 + mi * 16 + quad * 4 + r;
                    const float v = acc[mi][ni][r] + bv;
                    if (split) atomicAdd(&C[(long)m * N + n], v);
                    else       C[(long)m * N + n] = v;
                    pgp[mi][r] += v * wpv;
                }
            }
        }
    }
    if (wpg) {
#pragma unroll
        for (int mi = 0; mi < 2; ++mi)
#pragma unroll
            for (int r = 0; r < 4; ++r) {
                float v = pgp[mi][r];
                v += __shfl_xor(v, 1); v += __shfl_xor(v, 2);
                v += __shfl_xor(v, 4); v += __shfl_xor(v, 8);
                if (col == 0) {
                    const int m = wv * 32 + mi * 16 + quad * 4 + r;
                    atomicAdd(&pgen_acc[m], v);
                }
            }
    }
}

// ---------------------------------------------------------------------------
// Pack A (= dec_out, 128x512 f32) into MFMA-fragment-ordered bf16:
// unit u = ((sl*8+mt)*4+q)*16+c  holds A[mt*16+c][sl*32+q*8 .. +8] (16B).
// ---------------------------------------------------------------------------
__global__ __launch_bounds__(256) void pack_a(
    const float* __restrict__ A, unsigned short* __restrict__ Apk)
{
    const int u  = blockIdx.x * 256 + threadIdx.x;  // 8192 units
    const int c  = u & 15;
    const int q  = (u >> 4) & 3;
    const int mt = (u >> 6) & 7;
    const int sl = u >> 9;
    const float* src = A + (long)(mt * 16 + c) * 512 + sl * 32 + q * 8;
    const float4 x = *(const float4*)src;
    const float4 y = *(const float4*)(src + 4);
    *(uint4*)(Apk + (long)u * 8) = make_uint4(pk2(x.x, x.y), pk2(x.z, x.w),
                                              pk2(y.x, y.y), pk2(y.z, y.w));
}

// ---------------------------------------------------------------------------
// Vocab GEMM v4: C[128 x N] = A @ W^T + bias, fused row-softmax partials.
// Block = 32 output cols x all 128 rows; 32KB LDS -> 5 blocks/CU (20 waves).
// Wave w owns rows [32w, 32w+32) x all 32 cols: A-fragments read once per
// block (128KB L2-hot), row stats purely in-wave. W staged wave-contiguously
// (one 2KB row per wave-instruction), XOR-swizzled, read once globally.
// ---------------------------------------------------------------------------
__global__ __launch_bounds__(256, 5) void vocab_gemm(
    const unsigned short* __restrict__ Apk, const float* __restrict__ W,
    const float* __restrict__ bias, float* __restrict__ C, int N,
    float* __restrict__ pm, float* __restrict__ ps, int nbn)
{
    __shared__ __align__(16) unsigned short Ws[32 * 512];  // 32 KB
    const int tid  = threadIdx.x;
    const int lane = tid & 63;
    const int w    = tid >> 6;
    const int quad = lane >> 4;
    const int c    = lane & 15;
    const int nb   = blockIdx.x;

    // ---- stage W[nb*32 .. +32)[0..512) -> bf16 LDS, swizzled (16B gran) ----
#pragma unroll
    for (int i = 0; i < 8; ++i) {
        const int r  = i * 4 + w;                       // local row 0..31
        const int rg = (nb * 32 + r < N) ? (nb * 32 + r) : (N - 1);
        const float* src = W + (long)rg * 512 + (lane << 3);
        const float4 x = *(const float4*)src;
        const float4 y = *(const float4*)(src + 4);
        const int a16 = (r << 6) + (lane ^ (r & 7));    // 16B-unit index
        *(uint4*)&Ws[a16 << 3] = make_uint4(pk2(x.x, x.y), pk2(x.z, x.w),
                                            pk2(y.x, y.y), pk2(y.z, y.w));
    }

    f32x4 acc[2][2];   // [mi][nj]
#pragma unroll
    for (int mi = 0; mi < 2; ++mi)
#pragma unroll
        for (int nj = 0; nj < 2; ++nj) acc[mi][nj] = (f32x4){0.f, 0.f, 0.f, 0.f};

    bf16x8 aA[2], aB[2];
    auto loadA = [&](int sl, bf16x8* dst) {
#pragma unroll
        for (int mi = 0; mi < 2; ++mi) {
            const int u = ((sl * 8 + (w * 2 + mi)) * 4 + quad) * 16 + c;
            dst[mi] = *(const bf16x8*)(Apk + (long)u * 8);
        }
    };
    loadA(0, aA);
    __syncthreads();

#pragma unroll
    for (int sl = 0; sl < 16; ++sl) {
        bf16x8* cur = (sl & 1) ? aB : aA;
        bf16x8* nxt = (sl & 1) ? aA : aB;
        if (sl + 1 < 16) loadA(sl + 1, nxt);
        const int uk = ((sl << 2) + quad) ^ (c & 7);
        const bf16x8 bF0 = *(const bf16x8*)&Ws[((c << 6) + uk) << 3];
        const bf16x8 bF1 = *(const bf16x8*)&Ws[((((16 + c)) << 6) + uk) << 3];
        acc[0][0] = __builtin_amdgcn_mfma_f32_16x16x32_bf16(cur[0], bF0, acc[0][0], 0, 0, 0);
        acc[0][1] = __builtin_amdgcn_mfma_f32_16x16x32_bf16(cur[0], bF1, acc[0][1], 0, 0, 0);
        acc[1][0] = __builtin_amdgcn_mfma_f32_16x16x32_bf16(cur[1], bF0, acc[1][0], 0, 0, 0);
        acc[1][1] = __builtin_amdgcn_mfma_f32_16x16x32_bf16(cur[1], bF1, acc[1][1], 0, 0, 0);
    }

    // ---- epilogue: store logits + in-wave per-row stats (max, exp-sum) ----
    const int n0 = nb * 32 + c;
    const int n1 = nb * 32 + 16 + c;
    const bool ok0 = (n0 < N), ok1 = (n1 < N);
    const float bv0 = bias[ok0 ? n0 : (N - 1)];
    const float bv1 = bias[ok1 ? n1 : (N - 1)];
#pragma unroll
    for (int mi = 0; mi < 2; ++mi) {
#pragma unroll
        for (int r = 0; r < 4; ++r) {
            const int m = w * 32 + mi * 16 + quad * 4 + r;
            const float v0 = acc[mi][0][r] + bv0;
            const float v1 = acc[mi][1][r] + bv1;
            if (ok0) C[(long)m * N + n0] = v0;
            if (ok1) C[(long)m * N + n1] = v1;
            float mx = fmaxf(ok0 ? v0 : -3.0e38f, ok1 ? v1 : -3.0e38f);
            mx = fmaxf(mx, __shfl_xor(mx, 1));
            mx = fmaxf(mx, __shfl_xor(mx, 2));
            mx = fmaxf(mx, __shfl_xor(mx, 4));
            mx = fmaxf(mx, __shfl_xor(mx, 8));
            float sv = (ok0 ? __expf(v0 - mx) : 0.f) + (ok1 ? __expf(v1 - mx) : 0.f);
            sv += __shfl_xor(sv, 1); sv += __shfl_xor(sv, 2);
            sv += __shfl_xor(sv, 4); sv += __shfl_xor(sv, 8);
            if (c == 0) {
                pm[(long)m * nbn + nb] = mx;
                ps[(long)m * nbn + nb] = sv;
            }
        }
    }
}

// Merge the nblk per-panel row stats into per-row (M, S). grid = 128 rows.
__global__ __launch_bounds__(256) void row_merge(
    const float* __restrict__ pm, const float* __restrict__ ps, int nblk,
    float* __restrict__ Mrow, float* __restrict__ Srow)
{
    __shared__ float sred[4];
    __shared__ float sM;
    const int b = blockIdx.x, tid = threadIdx.x;
    const float* pmb = pm + (long)b * nblk;
    const float* psb = ps + (long)b * nblk;

    float m = -3.0e38f;
    for (int i = tid; i < nblk; i += 256) m = fmaxf(m, pmb[i]);
#pragma unroll
    for (int off = 32; off > 0; off >>= 1) m = fmaxf(m, __shfl_down(m, off));
    if ((tid & 63) == 0) sred[tid >> 6] = m;
    __syncthreads();
    if (tid == 0) sM = fmaxf(fmaxf(sred[0], sred[1]), fmaxf(sred[2], sred[3]));
    __syncthreads();
    const float M = sM;

    float s = 0.f;
    for (int i = tid; i < nblk; i += 256) s += psb[i] * __expf(pmb[i] - M);
#pragma unroll
    for (int off = 32; off > 0; off >>= 1) s += __shfl_down(s, off);
    if ((tid & 63) == 0) sred[tid >> 6] = s;
    __syncthreads();
    if (tid == 0) {
        Mrow[b] = M;
        Srow[b] = sred[0] + sred[1] + sred[2] + sred[3];
    }
}

// Elementwise LSTM cell over the accumulated gates buffer [128 x 2048]
// (i,f,g,o column-stacked). b_ih was added by the gates GEMM; add b_hh here.
__global__ __launch_bounds__(256) void lstm_cell(
    const float* __restrict__ gates, const float* __restrict__ bhh,
    const float* __restrict__ c0,
    float* __restrict__ h1, float* __restrict__ c1)
{
    const int idx = blockIdx.x * 256 + threadIdx.x;  // 65536 = 128*512
    const int m = idx >> 9;
    const int h = idx & 511;
    const float* g = gates + (long)m * 2048;
    const float iv = sigmoid_f(g[h]        + bhh[h]);
    const float fv = sigmoid_f(g[512 + h]  + bhh[512 + h]);
    const float gv = tanh_f   (g[1024 + h] + bhh[1024 + h]);
    const float ov = sigmoid_f(g[1536 + h] + bhh[1536 + h]);
    const float c = fv * c0[idx] + iv * gv;
    c1[idx] = c;
    h1[idx] = ov * tanh_f(c);
}

// e[b,s] = sum_h tanh(sf[b,s,h] + dec_fea[b,h] + wc*cov[b,s]) * v_att[h]
__global__ __launch_bounds__(256) void attn_scores(
    const float* __restrict__ sfeat, const float* __restrict__ decfea,
    const float* __restrict__ cov, const float* __restrict__ wc,
    const float* __restrict__ vatt, float* __restrict__ e)
{
    const int lane = threadIdx.x & 63;
    const int pair = blockIdx.x * 4 + (threadIdx.x >> 6);  // b*400+s
    const int b = pair / 400;
    const float cc = wc[0] * cov[pair];
    const float* sp = sfeat + ((long)pair << 9) + (lane << 3);
    const float* dp = decfea + (b << 9) + (lane << 3);
    const float* vp = vatt + (lane << 3);
    const float4 s0 = *(const float4*)sp, s1 = *(const float4*)(sp + 4);
    const float4 d0 = *(const float4*)dp, d1 = *(const float4*)(dp + 4);
    const float4 v0 = *(const float4*)vp, v1 = *(const float4*)(vp + 4);
    float acc = tanh_f(s0.x + d0.x + cc) * v0.x
              + tanh_f(s0.y + d0.y + cc) * v0.y
              + tanh_f(s0.z + d0.z + cc) * v0.z
              + tanh_f(s0.w + d0.w + cc) * v0.w
              + tanh_f(s1.x + d1.x + cc) * v1.x
              + tanh_f(s1.y + d1.y + cc) * v1.y
              + tanh_f(s1.z + d1.z + cc) * v1.z
              + tanh_f(s1.w + d1.w + cc) * v1.w;
#pragma unroll
    for (int off = 32; off > 0; off >>= 1) acc += __shfl_down(acc, off);
    if (lane == 0) e[pair] = acc;
}

// Masked softmax over S per batch row + coverage update; also zeroes ctx accum.
__global__ __launch_bounds__(256) void attn_softmax(
    const float* __restrict__ e, const float* __restrict__ mask,
    const float* __restrict__ cov,
    float* __restrict__ attn, float* __restrict__ covnew, float* __restrict__ ctx)
{
    __shared__ float sm[4], sps[4], spms[4];
    const int b = blockIdx.x, tid = threadIdx.x;
    ctx[(b << 9) + tid] = 0.f;
    ctx[(b << 9) + 256 + tid] = 0.f;

    float vals[2], msk[2];
    float m = -3.0e38f;
#pragma unroll
    for (int it = 0; it < 2; ++it) {
        const int s = tid + (it << 8);
        float mk = 0.f, v = -3.0e38f;
        if (s < 400) {
            mk = mask[b * 400 + s];
            v = (mk > 0.f) ? e[b * 400 + s] : -1.0e9f;
        }
        vals[it] = v; msk[it] = mk;
        m = fmaxf(m, v);
    }
#pragma unroll
    for (int off = 32; off > 0; off >>= 1) m = fmaxf(m, __shfl_down(m, off));
    if ((tid & 63) == 0) sm[tid >> 6] = m;
    __syncthreads();
    const float M = fmaxf(fmaxf(sm[0], sm[1]), fmaxf(sm[2], sm[3]));

    float p[2], sp = 0.f, spm = 0.f;
#pragma unroll
    for (int it = 0; it < 2; ++it) {
        const int s = tid + (it << 8);
        float pv = 0.f;
        if (s < 400) pv = __expf(vals[it] - M);
        p[it] = pv; sp += pv; spm += pv * msk[it];
    }
#pragma unroll
    for (int off = 32; off > 0; off >>= 1) {
        sp += __shfl_down(sp, off);
        spm += __shfl_down(spm, off);
    }
    if ((tid & 63) == 0) { sps[tid >> 6] = sp; spms[tid >> 6] = spm; }
    __syncthreads();
    const float SP = sps[0] + sps[1] + sps[2] + sps[3];
    const float SPM = spms[0] + spms[1] + spms[2] + spms[3];
    const float inv = 1.0f / (SPM + 1e-12f * SP);
#pragma unroll
    for (int it = 0; it < 2; ++it) {
        const int s = tid + (it << 8);
        if (s < 400) {
            const float a = p[it] * msk[it] * inv;
            attn[b * 400 + s] = a;
            covnew[b * 400 + s] = cov[b * 400 + s] + a;
        }
    }
}

// ctx[b,h] += sum over an s-chunk of attn[b,s]*states[b,s,h]; 4 chunks per b
__global__ __launch_bounds__(256) void ctx_kernel(
    const float* __restrict__ attn, const float* __restrict__ states,
    float* __restrict__ ctx)
{
    const int bx = blockIdx.x;  // 512
    const int b = bx >> 2, chunk = bx & 3;
    const int tid = threadIdx.x;
    const int c = tid & 127;
    const int sh = tid >> 7;
    const int s0 = chunk * 100 + sh;
    const float* base = states + (long)b * 400 * 512;
    float4 acc = make_float4(0.f, 0.f, 0.f, 0.f);
    for (int i = 0; i < 50; ++i) {
        const int s = s0 + (i << 1);
        const float a = attn[b * 400 + s];
        const float4 st = *(const float4*)(base + (long)s * 512 + (c << 2));
        acc.x = fmaf(a, st.x, acc.x);
        acc.y = fmaf(a, st.y, acc.y);
        acc.z = fmaf(a, st.z, acc.z);
        acc.w = fmaf(a, st.w, acc.w);
    }
    float* cp = ctx + (b << 9) + (c << 2);
    atomicAdd(cp + 0, acc.x);
    atomicAdd(cp + 1, acc.y);
    atomicAdd(cp + 2, acc.z);
    atomicAdd(cp + 3, acc.w);
}

// final[b, v<V] = p_gen*softmax(logits); final[b, V..VEXT) = 0.
// Uses premerged per-row (M, S); computes p_gen; block (0,b) writes o_pgen.
__global__ __launch_bounds__(256) void final_write(
    const float* __restrict__ logits, const float* __restrict__ Mrow,
    const float* __restrict__ Srow, const float* __restrict__ pgen_acc,
    const float* __restrict__ bpg, float* __restrict__ final,
    float* __restrict__ o_pgen)
{
    const int b = blockIdx.y;
    const int tid = threadIdx.x;
    const float M = Mrow[b];
    const float S = Srow[b];
    const float pg = sigmoid_f(pgen_acc[b] + bpg[0]);
    if (blockIdx.x == 0 && tid == 0) o_pgen[b] = pg;

    const int v0 = (blockIdx.x * 256 + tid) << 2;
    if (v0 >= VX_) return;
    const float sc = pg / S;
    const float* row = logits + (long)b * V_;
    float* out = final + (long)b * VX_ + v0;
#pragma unroll
    for (int j = 0; j < 4; ++j) {
        const int v = v0 + j;
        if (v < VX_) out[j] = (v < V_) ? __expf(row[v] - M) * sc : 0.f;
    }
}

// scatter-add copy distribution
__global__ __launch_bounds__(256) void scatter_kernel(
    const int* __restrict__ ids, const float* __restrict__ attn,
    const float* __restrict__ pgen, float* __restrict__ final)
{
    const int s = blockIdx.x * 256 + threadIdx.x;
    const int b = blockIdx.y;
    if (s < 400) {
        const float v = (1.0f - pgen[b]) * attn[b * 400 + s];
        atomicAdd(final + (long)b * VX_ + ids[b * 400 + s], v);
    }
}

extern "C" void kernel_launch(void* const* d_in, const int* in_sizes, int n_in,
                              void* d_out, int out_size, void* d_ws, size_t ws_size,
                              hipStream_t stream)
{
    const float* input_emb  = (const float*)d_in[0];
    const float* input_feed = (const float*)d_in[1];
    const float* hidden     = (const float*)d_in[2];
    const float* context    = (const float*)d_in[3];
    const float* states     = (const float*)d_in[4];
    const float* sfeat      = (const float*)d_in[5];
    const float* mask       = (const float*)d_in[6];
    const float* cov        = (const float*)d_in[7];
    const int*   src_ids    = (const int*)d_in[8];
    const float* W_ic  = (const float*)d_in[9];
    const float* b_ic  = (const float*)d_in[10];
    const float* W_ih  = (const float*)d_in[11];
    const float* W_hh  = (const float*)d_in[12];
    const float* b_ih  = (const float*)d_in[13];
    const float* b_hh  = (const float*)d_in[14];
    const float* W_dec = (const float*)d_in[15];
    const float* b_att = (const float*)d_in[16];
    const float* v_att = (const float*)d_in[17];
    const float* w_c   = (const float*)d_in[18];
    const float* W_out = (const float*)d_in[19];
    const float* b_out = (const float*)d_in[20];
    const float* W_pg  = (const float*)d_in[21];
    const float* b_pg  = (const float*)d_in[22];
    const float* W_v   = (const float*)d_in[23];
    const float* b_v   = (const float*)d_in[24];

    float* out = (float*)d_out;
    float* o_final = out + OFF_FINAL;
    float* o_pgen  = out + OFF_PGEN;
    float* o_attn  = out + OFF_ATTN;
    float* o_cov   = out + OFF_COV;
    float* o_h1    = out + OFF_H1;
    float* o_c1    = out + OFF_C1;
    float* o_dec   = out + OFF_DEC;

    // ws layout (floats). Early phase: w_x [0,65536) w_decfea [65536,131072)
    // w_gates [131072,393216) w_e [393344,444544) w_ctx [444544,510080).
    // Vocab phase (after those die): w_pm [0,201088) w_ps [201088,402176).
    // Stable tail: w_logits [510080,6942976) w_apk [6942976,6975744)
    // Mrow/Srow/pga at 6975744/6975872/6976000.
    float* ws = (float*)d_ws;
    float* w_x      = ws;
    float* w_decfea = ws + 65536;
    float* w_gates  = ws + 131072;
    float* w_pm     = ws;             // reuses dead early-phase region
    float* w_ps     = ws + 201088;
    float* w_e      = ws + 393344;
    float* w_ctx    = ws + 444544;
    float* w_logits = ws + 510080;
    unsigned short* w_apk = (unsigned short*)(ws + 6942976);
    float* w_Mrow   = ws + 6975744;
    float* w_Srow   = ws + 6975872;
    float* w_pga    = ws + 6976000;

    const dim3 blk(256);
    // zero split-K accumulators + o_dec + pgen accumulator
    zero_ws<<<385, blk, 0, stream>>>((float4*)ws, (float4*)o_dec, (float4*)w_pga);
    // x = [emb, feed] @ W_ic^T + b_ic   (split-K: 8 n-tiles x 8 chunks)
    gemm_mfma<4><<<dim3(8, 8), blk, 0, stream>>>(
        input_emb, W_ic, 1024, 0, input_feed, W_ic, 1024, 512,
        b_ic, w_x, 512, nullptr, nullptr);
    // gates = x @ W_ih^T + h0 @ W_hh^T + b_ih   (split-K: 32 n-tiles x 4 chunks)
    gemm_mfma<4><<<dim3(32, 4), blk, 0, stream>>>(
        w_x, W_ih, 512, 0, hidden, W_hh, 512, 0,
        b_ih, w_gates, 2048, nullptr, nullptr);
    // LSTM cell (adds b_hh) -> h1, c1
    lstm_cell<<<256, blk, 0, stream>>>(w_gates, b_hh, context, o_h1, o_c1);
    // dec_fea = h1 @ W_dec^T + b_att   (split-K: 8 x 4)
    gemm_mfma<4><<<dim3(8, 4), blk, 0, stream>>>(
        o_h1, W_dec, 512, 0, nullptr, nullptr, 0, 0,
        b_att, w_decfea, 512, nullptr, nullptr);
    // attention
    attn_scores<<<12800, blk, 0, stream>>>(sfeat, w_decfea, cov, w_c, v_att, w_e);
    attn_softmax<<<128, blk, 0, stream>>>(w_e, mask, cov, o_attn, o_cov, w_ctx);
    ctx_kernel<<<512, blk, 0, stream>>>(o_attn, states, w_ctx);
    // dec_out = [h1, ctx] @ W_out^T + b_out   (split-K 8 x 8, fused p_gen dot)
    gemm_mfma<4><<<dim3(8, 8), blk, 0, stream>>>(
        o_h1, W_out, 1024, 0, w_ctx, W_out, 1024, 512,
        b_out, o_dec, 512, W_pg, w_pga);
    // pack dec_out into MFMA-fragment bf16 layout (L2-resident)
    pack_a<<<32, blk, 0, stream>>>(o_dec, w_apk);
    // vocab logits + fused row softmax partials (1571 blocks, 5/CU)
    vocab_gemm<<<NBN_, blk, 0, stream>>>(
        w_apk, W_v, b_v, w_logits, V_, w_pm, w_ps, NBN_);
    // merge per-panel stats -> per-row (M, S)
    row_merge<<<128, blk, 0, stream>>>(w_pm, w_ps, NBN_, w_Mrow, w_Srow);
    final_write<<<dim3(50, 128), blk, 0, stream>>>(w_logits, w_Mrow, w_Srow,
                                                   w_pga, b_pg, o_final, o_pgen);
    scatter_kernel<<<dim3(2, 128), blk, 0, stream>>>(src_ids, o_attn, o_pgen, o_final);
}